// Round 8
// baseline (592.007 us; speedup 1.0000x reference)
//
#include <hip/hip_runtime.h>

#define D   256
#define WR  129          // D/2 + 1
#define B   64
static constexpr long PL = (long)D * D * WR;   // one output plane: 8,454,144 floats

// ===========================================================================
// Radix-2 Stockham FFT, 256-point, one wave per transform, 4 transforms per
// block, LDS ping-pong. (verbatim from verified round-4 kernel)
// ===========================================================================
__global__ void __launch_bounds__(256) row_fft_kernel(const float* __restrict__ imgs,
                                                      float2* __restrict__ F1T) {
    __shared__ float2 Xs[4][D];
    __shared__ float2 Ys[4][D];
    __shared__ float2 tws[128];

    const int t = threadIdx.x;
    const int f = t >> 6;          // transform id within block
    const int r = t & 63;          // lane within transform
    const int blk = blockIdx.x;
    const int b   = blk >> 5;              // 32 blocks per image
    const int rp  = ((blk & 31) << 2) + f; // row pair: rows 2rp, 2rp+1

    if (t < 128) {
        float s, c;
        sincospif(-(float)t * (1.0f / 128.0f), &s, &c);
        tws[t] = make_float2(c, s);
    }

    {
        const float* r0 = imgs + ((size_t)(b * D + 2 * rp)) * D;
        const float* r1 = r0 + D;
        #pragma unroll
        for (int j = 0; j < 4; ++j) {
            const int n = r + 64 * j;
            Xs[f][n] = make_float2(r0[n], r1[n]);
        }
    }
    __syncthreads();

    float2* Xf = Xs[f];
    float2* Yf = Ys[f];
    #pragma unroll
    for (int st = 0; st < 8; ++st) {
        float2* src = (st & 1) ? Yf : Xf;
        float2* dst = (st & 1) ? Xf : Yf;
        const int sB = 1 << st;
        #pragma unroll
        for (int hh = 0; hh < 2; ++hh) {
            const int u  = r + 64 * hh;
            const int pm = u & ~(sB - 1);
            const float2 a  = src[u];
            const float2 bv = src[u + 128];
            const float2 w  = tws[pm];
            const float dx = a.x - bv.x, dy = a.y - bv.y;
            const int o = u + pm;
            dst[o]      = make_float2(a.x + bv.x, a.y + bv.y);
            dst[o + sB] = make_float2(dx * w.x - dy * w.y, dx * w.y + dy * w.x);
        }
        __syncthreads();
    }

    for (int k = r; k <= 128; k += 64) {
        const float2 zk = Xf[k];
        const float2 zm = Xf[(256 - k) & 255];
        const float4 o4 = make_float4(0.5f * (zk.x + zm.x), 0.5f * (zk.y - zm.y),
                                      0.5f * (zk.y + zm.y), -0.5f * (zk.x - zm.x));
        *(float4*)&F1T[((size_t)(b * WR + k)) * D + 2 * rp] = o4;
    }
}

__global__ void __launch_bounds__(256) col_fft_kernel(const float2* __restrict__ F1T,
                                                      const float* __restrict__ ctf,
                                                      const float* __restrict__ hwShiftAngs,
                                                      float4* __restrict__ F4) {
    __shared__ float2 Xs[4][D];
    __shared__ float2 Ys[4][D];
    __shared__ float2 tws[128];

    const int t = threadIdx.x;
    const int f = t >> 6;
    const int r = t & 63;
    const int c = blockIdx.x * 4 + f;   // b*129 + x
    const int b = c / WR;
    const int x = c - b * WR;

    if (t < 128) {
        float s, cc;
        sincospif(-(float)t * (1.0f / 128.0f), &s, &cc);
        tws[t] = make_float2(cc, s);
    }

    {
        const float2* src = F1T + (size_t)c * D;
        #pragma unroll
        for (int j = 0; j < 4; ++j) {
            const int n = r + 64 * j;
            Xs[f][n] = src[n];
        }
    }
    __syncthreads();

    float2* Xf = Xs[f];
    float2* Yf = Ys[f];
    #pragma unroll
    for (int st = 0; st < 8; ++st) {
        float2* src = (st & 1) ? Yf : Xf;
        float2* dst = (st & 1) ? Xf : Yf;
        const int sB = 1 << st;
        #pragma unroll
        for (int hh = 0; hh < 2; ++hh) {
            const int u  = r + 64 * hh;
            const int pm = u & ~(sB - 1);
            const float2 a  = src[u];
            const float2 bv = src[u + 128];
            const float2 w  = tws[pm];
            const float dx = a.x - bv.x, dy = a.y - bv.y;
            const int o = u + pm;
            dst[o]      = make_float2(a.x + bv.x, a.y + bv.y);
            dst[o + sB] = make_float2(dx * w.x - dy * w.y, dx * w.y + dy * w.x);
        }
        __syncthreads();
    }

    const float sy = hwShiftAngs[b * 2 + 0];
    const float sx = hwShiftAngs[b * 2 + 1];

    #pragma unroll
    for (int j = 0; j < 4; ++j) {
        const int tt = r + 64 * j;                 // frequency index (pre-shift)
        const int h  = (tt + D / 2) & (D - 1);     // fftshifted row
        const float ky = (float)(h - D / 2);
        const float2 z = Xf[tt];
        const float ph = -2.0f * (ky * sy + (float)x * sx) * (1.0f / (float)D);
        float ps, pc;
        sincospif(ph, &ps, &pc);
        const float ore = z.x * pc - z.y * ps;
        const float oim = z.x * ps + z.y * pc;
        const size_t o = (size_t)(b * D + h) * WR + x;
        const float cf = ctf[o];
        F4[o] = make_float4(cf * ore, cf * oim, cf * cf, 0.f);
    }
}

// ===========================================================================
// Kernel 3: LDS-tiled SCATTER, 8x8x8 tile per block. Candidate-set logic
// identical to the verified round-5/7 kernels. DS-serialization fixes:
//  - AoS accumulator sAcc[copy][li*4 + {N,I,W,C}]: a corner's 4 atomics hit
//    4 different banks (was 4x same-bank with separate arrays).
//  - 4 copies by (ix&1, iy&1) with +4-float pad (copy stride = 4 banks):
//    corner-sharing lanes (t, t+1, t+16, t+17) write distinct addresses on
//    distinct banks -> no same-address serialization.
//  - both fold-passes' F4 loads issued (uniform-branch) before corner work.
// ===========================================================================
#define TS 8
#define CSTRIDE 2052   // 512*4 + 4 pad -> copy offset = 4 banks

__global__ void __launch_bounds__(256) scatter_tile_kernel(const float4* __restrict__ F4,
                                                           const float* __restrict__ rotMats,
                                                           float* __restrict__ out) {
    __shared__ float sAcc[4 * CSTRIDE];   // 32.8 KB
    __shared__ float aU[B][6];      // u=(R1,R4,R7) col_y, w=(R2,R5,R8) col_x
    __shared__ int   aBase[B];
    __shared__ int   na_s;

    const int t   = threadIdx.x;
    const int tx0 = blockIdx.x * TS;
    const int ty0 = blockIdx.y * TS;
    const int tz0 = blockIdx.z * TS;

    // centered tile center
    const float cx = (float)tx0 + 3.5f;
    const float cy = (float)ty0 + 3.5f - 128.f;
    const float cz = (float)tz0 + 3.5f - 128.f;

    for (int i = t; i < 4 * CSTRIDE; i += 256) sAcc[i] = 0.f;

    if (t < 64) {                     // wave 0: cull + compact
        const float* R = rotMats + t * 9;
        const float R0 = R[0], R1 = R[1], R2 = R[2];
        const float R3 = R[3], R4 = R[4], R5 = R[5];
        const float R6 = R[6], R7 = R[7], R8 = R[8];
        const float qn = R0 * cz + R3 * cy + R6 * cx;
        const float mz = 4.5f * (fabsf(R0) + fabsf(R3) + fabsf(R6));
        const float cc2 = cz * cz + cy * cy + cx * cx;
        const bool pass = (fabsf(qn) <= mz) && (cc2 <= 35683.2f);   // 188.9^2
        const unsigned long long m = __ballot(pass);
        if (t == 0) na_s = (int)__popcll(m);
        if (pass) {
            const int a = (int)__popcll(m & ((1ull << t) - 1ull));
            aU[a][0] = R1; aU[a][1] = R4; aU[a][2] = R7;
            aU[a][3] = R2; aU[a][4] = R5; aU[a][5] = R8;
            aBase[a] = t * (D * WR);
        }
    }
    __syncthreads();

    const int na    = na_s;
    const int iy    = t >> 4;        // 0..15 (ky offset in window)
    const int ix    = t & 15;        // 0..15 (kx offset in window)
    float* myAcc    = &sAcc[(((ix & 1) | ((iy & 1) << 1))) * CSTRIDE];
    const int xlim  = min(tx0 + 7, 128) - tx0;   // 7, or less in last x-tile

    for (int a = 0; a < na; ++a) {
        const float u0 = aU[a][0], u1 = aU[a][1], u2 = aU[a][2];
        const float w0 = aU[a][3], w1 = aU[a][4], w2 = aU[a][5];
        const int  base = aBase[a];

        // window centers: ky = r.u, kx = r.w (orthonormal cols); Hölder bound
        const float cu  = cz * u0 + cy * u1 + cx * u2;
        const float cw  = cz * w0 + cy * w1 + cx * w2;
        const float wky = 4.5f * (fabsf(u0) + fabsf(u1) + fabsf(u2));  // <= 7.795
        const float wkx = 4.5f * (fabsf(w0) + fabsf(w1) + fabsf(w2));
        const int ky00 = (int)ceilf(cu - wky);    // fold + window (16 wide)
        const int kx00 = (int)ceilf(cw - wkx);
        const int ky01 = (int)ceilf(-cu - wky);   // fold - window
        const int kx01 = (int)ceilf(-cw - wkx);

        // uniform pass-liveness (same for all lanes in the block)
        const bool live0 = !(ky00 > 127 || ky00 + 15 < -128 || kx00 > 128 || kx00 + 15 < 0);
        const bool live1 = !(ky01 > 127 || ky01 + 15 < -128 || kx01 > 128 || kx01 + 15 < 0);

        int  kyv[2], kxv[2];
        bool okv[2];
        kyv[0] = ky00 + iy; kxv[0] = kx00 + ix;
        kyv[1] = ky01 + iy; kxv[1] = kx01 + ix;
        okv[0] = live0 & (kyv[0] >= -128) & (kyv[0] <= 127) & (kxv[0] >= 0) & (kxv[0] <= 128);
        okv[1] = live1 & (kyv[1] >= -128) & (kyv[1] <= 127) & (kxv[1] >= 0) & (kxv[1] <= 128) &
                 !((kyv[1] >= ky00) & (kyv[1] <= ky00 + 15) &
                   (kxv[1] >= kx00) & (kxv[1] <= kx00 + 15));   // dedup vs pass 0

        // issue both loads up front (clamped addr; use predicated by okv)
        float4 vv[2];
        if (live0) {
            const int kyc = min(max(kyv[0], -128), 127);
            const int kxc = min(max(kxv[0], 0), 128);
            vv[0] = F4[base + (kyc + 128) * WR + kxc];
        }
        if (live1) {
            const int kyc = min(max(kyv[1], -128), 127);
            const int kxc = min(max(kxv[1], 0), 128);
            vv[1] = F4[base + (kyc + 128) * WR + kxc];
        }

        #pragma unroll
        for (int p = 0; p < 2; ++p) {
            if (p == 0 && !live0) continue;
            if (p == 1 && !live1) continue;
            if (!okv[p]) continue;

            const float kyf = (float)kyv[p], kxf = (float)kxv[p];
            float rz = u0 * kyf + w0 * kxf;
            float ry = u1 * kyf + w1 * kxf;
            float rx = u2 * kyf + w2 * kxf;
            const bool neg = rx < 0.f;            // Hermitian fold (round-1 rule)
            if (neg) { rz = -rz; ry = -ry; rx = -rx; }
            const float zc = rz + 128.f;
            const float yc = ry + 128.f;
            const float xc = rx;
            const float z0f = floorf(zc), y0f = floorf(yc), x0f = floorf(xc);
            const int z0 = (int)z0f, y0 = (int)y0f, x0 = (int)x0f;
            const int iz  = z0 - tz0;             // each in [-1, 8] if touching
            const int iyv = y0 - ty0;
            const int ixv = x0 - tx0;
            // quick reject: no corner lands in this tile
            if (iz < -1 || iz > 7 || iyv < -1 || iyv > 7 || ixv < -1 || ixv > xlim) continue;

            const float fz = zc - z0f, fy = yc - y0f, fx = xc - x0f;
            const float4 v = vv[p];
            const float vre = v.x;
            const float vim = neg ? -v.y : v.y;
            const float vcs = v.z;

            // branchless per-axis weights (out-of-tile => 0); indices only
            // consumed when the corner weight is > 0 (then clamp is identity)
            float wz_[2], wy_[2], wx_[2];
            int   lz_[2], ly_[2], lx_[2];
            wz_[0] = (iz  >= 0)        ? (1.f - fz) : 0.f;  lz_[0] = max(iz, 0);
            wz_[1] = (iz  <= 6)        ? fz         : 0.f;  lz_[1] = min(iz + 1, 7);
            wy_[0] = (iyv >= 0)        ? (1.f - fy) : 0.f;  ly_[0] = max(iyv, 0);
            wy_[1] = (iyv <= 6)        ? fy         : 0.f;  ly_[1] = min(iyv + 1, 7);
            wx_[0] = (ixv >= 0)        ? (1.f - fx) : 0.f;  lx_[0] = max(ixv, 0);
            wx_[1] = (ixv + 1 <= xlim) ? fx         : 0.f;  lx_[1] = min(ixv + 1, 7);

            #pragma unroll
            for (int dz = 0; dz < 2; ++dz) {
                #pragma unroll
                for (int dy = 0; dy < 2; ++dy) {
                    const float wzy = wz_[dz] * wy_[dy];
                    const int   lzy = (lz_[dz] << 6) | (ly_[dy] << 3);
                    #pragma unroll
                    for (int dx = 0; dx < 2; ++dx) {
                        const float wgt = wzy * wx_[dx];
                        if (wgt > 0.f) {          // skip zero-weight corners
                            float* dst = myAcc + ((lzy | lx_[dx]) << 2);
                            atomicAdd(dst + 0, wgt * vre);
                            atomicAdd(dst + 1, wgt * vim);
                            atomicAdd(dst + 2, wgt);
                            atomicAdd(dst + 3, wgt * vcs);
                        }
                    }
                }
            }
        }
    }
    __syncthreads();

    #pragma unroll
    for (int rr = 0; rr < 2; ++rr) {
        const int li = t + 256 * rr;
        const int xi = tx0 + (li & 7);
        if (xi > 128) continue;
        const int yi = ty0 + ((li >> 3) & 7);
        const int zi = tz0 + (li >> 6);
        const long idx = (long)zi * (D * WR) + (long)yi * WR + xi;
        const int s = li << 2;
        const float4 c0 = *(const float4*)&sAcc[s];
        const float4 c1 = *(const float4*)&sAcc[s + CSTRIDE];
        const float4 c2 = *(const float4*)&sAcc[s + 2 * CSTRIDE];
        const float4 c3 = *(const float4*)&sAcc[s + 3 * CSTRIDE];
        out[idx]          = (c0.x + c1.x) + (c2.x + c3.x);
        out[PL + idx]     = (c0.y + c1.y) + (c2.y + c3.y);
        out[2 * PL + idx] = (c0.z + c1.z) + (c2.z + c3.z);
        out[3 * PL + idx] = (c0.w + c1.w) + (c2.w + c3.w);
    }
}

// ---------------------------------------------------------------------------
extern "C" void kernel_launch(void* const* d_in, const int* in_sizes, int n_in,
                              void* d_out, int out_size, void* d_ws, size_t ws_size,
                              hipStream_t stream) {
    const float* imgs    = (const float*)d_in[0];   // [B, D, D]
    const float* ctf     = (const float*)d_in[1];   // [B, D, WR]
    const float* rotMats = (const float*)d_in[2];   // [B, 3, 3]
    const float* hw      = (const float*)d_in[3];   // [B, 2]
    float* out = (float*)d_out;                     // [4, D, D, WR]

    float2* F1T = (float2*)d_ws;                                   // [B,WR,D] complex (16.9 MB)
    float4* F4  = (float4*)((char*)d_ws + (size_t)B * D * WR * 8); // [B,D,WR] float4 (33.8 MB)

    row_fft_kernel<<<B * D / 2 / 4, 256, 0, stream>>>(imgs, F1T);
    col_fft_kernel<<<B * WR / 4, 256, 0, stream>>>(F1T, ctf, hw, F4);

    dim3 grid((WR + TS - 1) / TS, D / TS, D / TS);   // 17 x 32 x 32
    scatter_tile_kernel<<<grid, 256, 0, stream>>>(F4, rotMats, out);
}